// Round 1
// baseline (570.068 us; speedup 1.0000x reference)
//
#include <hip/hip_runtime.h>
#include <hip/hip_bf16.h>

#define NN 400
#define KMAX 64

struct PtrTable {
  const void* p[36];
  int off[37];
};

// ---------------------------------------------------------------------------
// Dtype detection: if inputs are bf16, even-indexed halfwords are plausible
// N(0,1) bf16 values; if fp32, even halfwords are mantissa bits (random exp).
// ---------------------------------------------------------------------------
__global__ void detect_dtype_k(const unsigned short* __restrict__ probe,
                               int* __restrict__ flag) {
  int lane = threadIdx.x;  // 64 threads
  unsigned short u = probe[lane * 2];
  int e = (u >> 7) & 0xFF;
  bool plaus = (u == 0) || (e >= 112 && e <= 132);
  unsigned long long m = __ballot(plaus);
  if (lane == 0) flag[0] = (__popcll(m) >= 48) ? 1 : 0;
}

// Convert all inputs (bf16 or fp32) to a contiguous fp32 region in workspace.
__global__ void convert_k(PtrTable pt, const int* __restrict__ flag,
                          float* __restrict__ dst) {
  bool isbf = flag[0] != 0;
  int total = pt.off[36];
  for (int i = blockIdx.x * blockDim.x + threadIdx.x; i < total;
       i += gridDim.x * blockDim.x) {
    int lo = 0, hi = 35;
    while (lo < hi) {
      int mid = (lo + hi + 1) >> 1;
      if (i >= pt.off[mid]) lo = mid; else hi = mid - 1;
    }
    int rel = i - pt.off[lo];
    float v;
    if (isbf) v = __bfloat162float(((const __hip_bfloat16*)pt.p[lo])[rel]);
    else      v = ((const float*)pt.p[lo])[rel];
    dst[i] = v;
  }
}

// ---------------------------------------------------------------------------
// CSR build: one wave per row, ballot-compaction of nonzero adjacency entries.
// Masked (-1e9) entries underflow to exactly 0 in the reference softmax, so
// sparse attention over these neighbor lists is numerically equivalent.
// ---------------------------------------------------------------------------
__global__ void build_csr_k(const float* __restrict__ adj,
                            int* __restrict__ colp, int* __restrict__ degp) {
  int row = blockIdx.x, lane = threadIdx.x;  // 64 threads
  int base = 0;
  for (int j0 = 0; j0 < NN; j0 += 64) {
    int j = j0 + lane;
    bool nz = (j < NN) && (adj[row * NN + j] != 0.0f);
    unsigned long long m = __ballot(nz);
    int offl = __popcll(m & ((1ull << lane) - 1ull));
    if (nz) {
      int pidx = base + offl;
      if (pidx < KMAX) colp[row * KMAX + pidx] = j;
    }
    base += __popcll(m);
  }
  if (lane == 0) degp[row] = base < KMAX ? base : KMAX;
}

// ---------------------------------------------------------------------------
// Spatial: one block per (b,s) graph. GAT1 (4 heads x 16, fp32 K/V in LDS,
// head loop) -> relu -> h1 (global fp32) -> GAT2 (1 head x 32, bf16 K/V in
// LDS) -> residual pad + LayerNorm -> sp (global fp32).
// ---------------------------------------------------------------------------
__global__ __launch_bounds__(256) void spatial_k(
    const float* __restrict__ xin, const float* __restrict__ g1,
    const float* __restrict__ g2, const float* __restrict__ spw,
    const int* __restrict__ colp, const int* __restrict__ degp,
    float* __restrict__ h1, float* __restrict__ spo) {
  __shared__ float xs[NN * 3];          //  4.8 KB
  __shared__ float kbuf[NN * 16];       // 25.6 KB (GAT2 aliases as bf16[400*32])
  __shared__ float vbuf[NN * 16];       // 25.6 KB
  __shared__ float w1s[768];            //  3.0 KB  g1 wq|bq|wk|bk|wv|bv
  __shared__ __hip_bfloat16 wq2s[2048]; //  4.0 KB
  __shared__ float bq2s[32];
  const int tid = threadIdx.x;
  const int bs = blockIdx.x;

  for (int e = tid; e < NN * 3; e += 256) xs[e] = xin[bs * NN * 3 + e];
  for (int e = tid; e < 768; e += 256) w1s[e] = g1[e];
  for (int e = tid; e < 2048; e += 256) wq2s[e] = __float2bfloat16(g2[e]);
  if (tid < 32) bq2s[tid] = g2[2048 + tid];
  __syncthreads();

  // ---- GAT1, per-head loop (dim 16, scale 1/4) ----
  for (int h = 0; h < 4; ++h) {
    const int co = h * 16;
    for (int e = tid; e < NN * 16; e += 256) {
      int n = e >> 4, c = e & 15;
      float x0 = xs[n * 3], x1 = xs[n * 3 + 1], x2 = xs[n * 3 + 2];
      int wc = co + c;
      kbuf[e] = w1s[448 + wc] + x0 * w1s[256 + wc] + x1 * w1s[320 + wc] + x2 * w1s[384 + wc];
      vbuf[e] = w1s[704 + wc] + x0 * w1s[512 + wc] + x1 * w1s[576 + wc] + x2 * w1s[640 + wc];
    }
    __syncthreads();
    for (int i = tid; i < NN; i += 256) {
      float x0 = xs[i * 3], x1 = xs[i * 3 + 1], x2 = xs[i * 3 + 2];
      float q[16], o[16];
      #pragma unroll
      for (int c = 0; c < 16; ++c) {
        int wc = co + c;
        q[c] = w1s[192 + wc] + x0 * w1s[wc] + x1 * w1s[64 + wc] + x2 * w1s[128 + wc];
        o[c] = 0.f;
      }
      int dg = degp[i];
      const int* cols = colp + i * KMAX;
      float m = -1e30f, l = 0.f;
      for (int e = 0; e < dg; ++e) {
        int j = cols[e];
        const float* kr = kbuf + j * 16;
        float s = 0.f;
        #pragma unroll
        for (int c = 0; c < 16; ++c) s += q[c] * kr[c];
        s *= 0.25f;
        float nm = fmaxf(m, s);
        float corr = __expf(m - nm);
        float p = __expf(s - nm);
        const float* vr = vbuf + j * 16;
        #pragma unroll
        for (int c = 0; c < 16; ++c) o[c] = o[c] * corr + p * vr[c];
        l = l * corr + p;
        m = nm;
      }
      float inv = 1.f / l;
      float* hr = h1 + ((size_t)bs * NN + i) * 64 + co;
      #pragma unroll
      for (int c = 0; c < 16; ++c) hr[c] = fmaxf(o[c] * inv, 0.f);  // relu
    }
    __syncthreads();
  }

  // ---- GAT2 K/V projection into bf16 LDS (aliasing kbuf/vbuf space) ----
  __hip_bfloat16* k2 = (__hip_bfloat16*)kbuf;  // [400][32]
  __hip_bfloat16* v2 = (__hip_bfloat16*)vbuf;
  const float* wk2 = g2 + 2080; const float* bk2 = g2 + 4128;
  const float* wv2 = g2 + 4160; const float* bv2 = g2 + 6208;
  for (int e = tid; e < NN * 32; e += 256) {
    int n = e >> 5, c = e & 31;
    const float* hr = h1 + ((size_t)bs * NN + n) * 64;
    float ka = bk2[c], va = bv2[c];
    for (int d = 0; d < 64; ++d) {
      float hv = hr[d];
      ka += hv * wk2[d * 32 + c];
      va += hv * wv2[d * 32 + c];
    }
    k2[e] = __float2bfloat16(ka);
    v2[e] = __float2bfloat16(va);
  }
  __syncthreads();

  // ---- GAT2 attention (dim 32, scale 1/sqrt(32)) + residual pad + LN ----
  const float rs32 = 0.17677669529663688f;
  for (int i = tid; i < NN; i += 256) {
    const float* hr = h1 + ((size_t)bs * NN + i) * 64;
    float q[32], o[32];
    #pragma unroll
    for (int c = 0; c < 32; ++c) { q[c] = bq2s[c]; o[c] = 0.f; }
    for (int d = 0; d < 64; ++d) {
      float hv = hr[d];
      #pragma unroll
      for (int c = 0; c < 32; ++c) q[c] += hv * __bfloat162float(wq2s[d * 32 + c]);
    }
    int dg = degp[i];
    const int* cols = colp + i * KMAX;
    float m = -1e30f, l = 0.f;
    for (int e = 0; e < dg; ++e) {
      int j = cols[e];
      float s = 0.f;
      #pragma unroll
      for (int c = 0; c < 32; ++c) s += q[c] * __bfloat162float(k2[j * 32 + c]);
      s *= rs32;
      float nm = fmaxf(m, s);
      float corr = __expf(m - nm);
      float p = __expf(s - nm);
      #pragma unroll
      for (int c = 0; c < 32; ++c) o[c] = o[c] * corr + p * __bfloat162float(v2[j * 32 + c]);
      l = l * corr + p;
      m = nm;
    }
    float inv = 1.f / l;
    float row[32];
    #pragma unroll
    for (int c = 0; c < 32; ++c) row[c] = o[c] * inv + (c < 3 ? xs[i * 3 + c] : 0.f);
    float mean = 0.f;
    #pragma unroll
    for (int c = 0; c < 32; ++c) mean += row[c];
    mean *= (1.f / 32.f);
    float var = 0.f;
    #pragma unroll
    for (int c = 0; c < 32; ++c) { float dd = row[c] - mean; var += dd * dd; }
    var *= (1.f / 32.f);
    float rinv = 1.f / sqrtf(var + 1e-6f);
    float* so = spo + ((size_t)bs * NN + i) * 32;
    #pragma unroll
    for (int c = 0; c < 32; ++c) so[c] = spw[c] * (row[c] - mean) * rinv + spw[32 + c];
  }
}

// ---------------------------------------------------------------------------
// Temporal transformer + fuse head: one block per (b,n) sequence (S=24, D=32).
// MHA(2 heads x 32) -> LN -> FF(32->64->32, exact gelu) -> LN -> mean over S,
// + mean over S of sp, final LN, dense -> out[b*400+n].
// ---------------------------------------------------------------------------
__global__ __launch_bounds__(128) void temporal_k(
    const float* __restrict__ sp, const float* __restrict__ tw,
    const int* __restrict__ flag, void* __restrict__ outp) {
  __shared__ float t_s[24 * 32];
  __shared__ float q_s[24 * 64];
  __shared__ float k_s[24 * 64];
  __shared__ float v_s[24 * 64];
  __shared__ float aw[2 * 24 * 24];
  __shared__ float att[24 * 64];
  __shared__ float x1s[24 * 32];
  __shared__ float f1s[24 * 64];
  __shared__ float tos[24 * 32];
  __shared__ float red[32];
  const int tid = threadIdx.x;
  const int b = blockIdx.x / NN, n = blockIdx.x % NN;

  const float* twq = tw;            const float* tbq = tw + 2048;
  const float* twk = tw + 2112;     const float* tbk = tw + 4160;
  const float* twv = tw + 4224;     const float* tbv = tw + 6272;
  const float* two = tw + 6336;     const float* tbo = tw + 8384;
  const float* fw1 = tw + 8416;     const float* fb1 = tw + 10464;
  const float* fw2 = tw + 10528;    const float* fb2 = tw + 12576;
  const float* l1g = tw + 12608;    const float* l1b = tw + 12640;
  const float* l2g = tw + 12672;    const float* l2b = tw + 12704;
  const float* fng = tw + 12736;    const float* fnb = tw + 12768;
  const float* fdw = tw + 12800;    const float* fdb = tw + 12832;

  for (int e = tid; e < 768; e += 128) {
    int s = e >> 5, c = e & 31;
    t_s[e] = sp[(((size_t)b * 24 + s) * NN + n) * 32 + c];
  }
  __syncthreads();

  // QKV: q[s][h*32+d] = sum_c t[s][c] * wq[c][h][d] + bq[h][d]
  for (int e = tid; e < 1536; e += 128) {
    int s = e >> 6, hk = e & 63;
    float qa = tbq[hk], ka = tbk[hk], va = tbv[hk];
    const float* tr = t_s + s * 32;
    #pragma unroll 8
    for (int c = 0; c < 32; ++c) {
      float tv = tr[c];
      qa += tv * twq[c * 64 + hk];
      ka += tv * twk[c * 64 + hk];
      va += tv * twv[c * 64 + hk];
    }
    q_s[e] = qa; k_s[e] = ka; v_s[e] = va;
  }
  __syncthreads();

  // scores + softmax over keys (scale 1/sqrt(32))
  if (tid < 48) {
    int h = tid / 24, qs = tid % 24;
    const float* qr = q_s + qs * 64 + h * 32;
    float sc[24];
    float mx = -1e30f;
    #pragma unroll
    for (int ss = 0; ss < 24; ++ss) {
      const float* kr = k_s + ss * 64 + h * 32;
      float s = 0.f;
      #pragma unroll
      for (int d = 0; d < 32; ++d) s += qr[d] * kr[d];
      s *= 0.17677669529663688f;
      sc[ss] = s;
      mx = fmaxf(mx, s);
    }
    float l = 0.f;
    #pragma unroll
    for (int ss = 0; ss < 24; ++ss) { float p = __expf(sc[ss] - mx); sc[ss] = p; l += p; }
    float inv = 1.f / l;
    float* ar = aw + (h * 24 + qs) * 24;
    #pragma unroll
    for (int ss = 0; ss < 24; ++ss) ar[ss] = sc[ss] * inv;
  }
  __syncthreads();

  // attention output
  for (int e = tid; e < 1536; e += 128) {
    int qs = e >> 6, hk = e & 63, h = hk >> 5;
    const float* ar = aw + (h * 24 + qs) * 24;
    float a = 0.f;
    #pragma unroll
    for (int ss = 0; ss < 24; ++ss) a += ar[ss] * v_s[ss * 64 + hk];
    att[e] = a;
  }
  __syncthreads();

  // output projection + residual
  for (int e = tid; e < 768; e += 128) {
    int s = e >> 5, c = e & 31;
    const float* ar = att + s * 64;
    float a = tbo[c];
    #pragma unroll 8
    for (int hk = 0; hk < 64; ++hk) a += ar[hk] * two[hk * 32 + c];
    x1s[e] = t_s[e] + a;
  }
  __syncthreads();
  if (tid < 24) {  // LN1
    float* r = x1s + tid * 32;
    float mean = 0.f;
    for (int c = 0; c < 32; ++c) mean += r[c];
    mean *= (1.f / 32.f);
    float var = 0.f;
    for (int c = 0; c < 32; ++c) { float d = r[c] - mean; var += d * d; }
    var *= (1.f / 32.f);
    float ri = 1.f / sqrtf(var + 1e-6f);
    for (int c = 0; c < 32; ++c) r[c] = l1g[c] * (r[c] - mean) * ri + l1b[c];
  }
  __syncthreads();

  // FF1 + exact gelu
  for (int e = tid; e < 1536; e += 128) {
    int s = e >> 6, j = e & 63;
    const float* xr = x1s + s * 32;
    float a = fb1[j];
    #pragma unroll 8
    for (int c = 0; c < 32; ++c) a += xr[c] * fw1[c * 64 + j];
    f1s[e] = 0.5f * a * (1.f + erff(a * 0.70710678118654752f));
  }
  __syncthreads();

  // FF2 + residual
  for (int e = tid; e < 768; e += 128) {
    int s = e >> 5, c = e & 31;
    const float* fr = f1s + s * 64;
    float a = fb2[c];
    #pragma unroll 8
    for (int j = 0; j < 64; ++j) a += fr[j] * fw2[j * 32 + c];
    tos[e] = x1s[e] + a;
  }
  __syncthreads();
  if (tid < 24) {  // LN2
    float* r = tos + tid * 32;
    float mean = 0.f;
    for (int c = 0; c < 32; ++c) mean += r[c];
    mean *= (1.f / 32.f);
    float var = 0.f;
    for (int c = 0; c < 32; ++c) { float d = r[c] - mean; var += d * d; }
    var *= (1.f / 32.f);
    float ri = 1.f / sqrtf(var + 1e-6f);
    for (int c = 0; c < 32; ++c) r[c] = l2g[c] * (r[c] - mean) * ri + l2b[c];
  }
  __syncthreads();

  // fuse: mean over S of sp (t_s) + mean over S of t_out (tos)
  if (tid < 32) {
    float ms = 0.f, mt = 0.f;
    for (int s = 0; s < 24; ++s) { ms += t_s[s * 32 + tid]; mt += tos[s * 32 + tid]; }
    red[tid] = (ms + mt) * (1.f / 24.f);
  }
  __syncthreads();
  if (tid == 0) {
    float mean = 0.f;
    for (int c = 0; c < 32; ++c) mean += red[c];
    mean *= (1.f / 32.f);
    float var = 0.f;
    for (int c = 0; c < 32; ++c) { float d = red[c] - mean; var += d * d; }
    var *= (1.f / 32.f);
    float ri = 1.f / sqrtf(var + 1e-6f);
    float acc = fdb[0];
    for (int c = 0; c < 32; ++c)
      acc += (fng[c] * (red[c] - mean) * ri + fnb[c]) * fdw[c];
    if (flag[0]) ((__hip_bfloat16*)outp)[blockIdx.x] = __float2bfloat16(acc);
    else         ((float*)outp)[blockIdx.x] = acc;
  }
}

// ---------------------------------------------------------------------------
extern "C" void kernel_launch(void* const* d_in, const int* in_sizes, int n_in,
                              void* d_out, int out_size, void* d_ws, size_t ws_size,
                              hipStream_t stream) {
  static const int sizes[36] = {
      230400, 160000,                         // inputs, adj
      192, 64, 192, 64, 192, 64,              // g1 wq bq wk bk wv bv
      2048, 32, 2048, 32, 2048, 32,           // g2 wq bq wk bk wv bv
      32, 32,                                 // sp_g sp_b
      2048, 64, 2048, 64, 2048, 64, 2048, 32, // t wq bq wk bk wv bv wo bo
      2048, 64, 2048, 32,                     // ff w1 b1 w2 b2
      32, 32, 32, 32, 32, 32,                 // ln1 g/b, ln2 g/b, fin g/b
      32, 1};                                 // fd_w fd_b
  PtrTable pt;
  int off = 0;
  for (int i = 0; i < 36; ++i) { pt.p[i] = d_in[i]; pt.off[i] = off; off += sizes[i]; }
  pt.off[36] = off;  // 410305 total fp32 elements

  char* ws = (char*)d_ws;
  int*   flag = (int*)ws;                       // [0,64)
  float* conv = (float*)(ws + 64);              // 410305 f -> ends 1,641,348
  int*   colp = (int*)(ws + 1835008);           // 400*64 ints
  int*   degp = (int*)(ws + 1835008 + 102400);  // 400 ints
  float* h1   = (float*)(ws + 2097152);         // 192*400*64 f = 19.66 MB
  float* spo  = (float*)(ws + 22020096);        // 192*400*32 f =  9.83 MB

  const float* cin  = conv;           // inputs
  const float* cadj = conv + 230400;  // adj
  const float* g1   = conv + 390400;  // g1 region (768)
  const float* g2   = conv + 391168;  // g2 region (6240)
  const float* spw  = conv + 397408;  // sp_g|sp_b (64)
  const float* twp  = conv + 397472;  // temporal region (12833)

  hipLaunchKernelGGL(detect_dtype_k, dim3(1), dim3(64), 0, stream,
                     (const unsigned short*)d_in[0], flag);
  hipLaunchKernelGGL(convert_k, dim3(512), dim3(256), 0, stream, pt,
                     (const int*)flag, conv);
  hipLaunchKernelGGL(build_csr_k, dim3(NN), dim3(64), 0, stream, cadj, colp, degp);
  hipLaunchKernelGGL(spatial_k, dim3(192), dim3(256), 0, stream, cin, g1, g2,
                     spw, (const int*)colp, (const int*)degp, h1, spo);
  hipLaunchKernelGGL(temporal_k, dim3(3200), dim3(128), 0, stream,
                     (const float*)spo, twp, (const int*)flag, d_out);
}

// Round 2
// 337.266 us; speedup vs baseline: 1.6903x; 1.6903x over previous
//
#include <hip/hip_runtime.h>
#include <hip/hip_bf16.h>

#define NN 400
#define KMAX 64

struct PtrTable {
  const void* p[36];
  int off[37];
};

__device__ __forceinline__ float bflo(unsigned u) {
  union { unsigned i; float f; } x; x.i = u << 16; return x.f;
}
__device__ __forceinline__ float bfhi(unsigned u) {
  union { unsigned i; float f; } x; x.i = u & 0xffff0000u; return x.f;
}
__device__ __forceinline__ unsigned short f2bf(float f) {
  __hip_bfloat16 b = __float2bfloat16(f);
  return *reinterpret_cast<unsigned short*>(&b);
}
__device__ __forceinline__ unsigned packbf(float a, float b) {
  return (unsigned)f2bf(a) | ((unsigned)f2bf(b) << 16);
}

// ---------------------------------------------------------------------------
__global__ void detect_dtype_k(const unsigned short* __restrict__ probe,
                               int* __restrict__ flag) {
  int lane = threadIdx.x;  // 64 threads
  unsigned short u = probe[lane * 2];
  int e = (u >> 7) & 0xFF;
  bool plaus = (u == 0) || (e >= 112 && e <= 132);
  unsigned long long m = __ballot(plaus);
  if (lane == 0) flag[0] = (__popcll(m) >= 48) ? 1 : 0;
}

__global__ void convert_k(PtrTable pt, const int* __restrict__ flag,
                          float* __restrict__ dst) {
  bool isbf = flag[0] != 0;
  int total = pt.off[36];
  for (int i = blockIdx.x * blockDim.x + threadIdx.x; i < total;
       i += gridDim.x * blockDim.x) {
    int lo = 0, hi = 35;
    while (lo < hi) {
      int mid = (lo + hi + 1) >> 1;
      if (i >= pt.off[mid]) lo = mid; else hi = mid - 1;
    }
    int rel = i - pt.off[lo];
    float v;
    if (isbf) v = __bfloat162float(((const __hip_bfloat16*)pt.p[lo])[rel]);
    else      v = ((const float*)pt.p[lo])[rel];
    dst[i] = v;
  }
}

__global__ void build_csr_k(const float* __restrict__ adj,
                            int* __restrict__ colp, int* __restrict__ degp) {
  int row = blockIdx.x, lane = threadIdx.x;  // 64 threads
  int base = 0;
  for (int j0 = 0; j0 < NN; j0 += 64) {
    int j = j0 + lane;
    bool nz = (j < NN) && (adj[row * NN + j] != 0.0f);
    unsigned long long m = __ballot(nz);
    int offl = __popcll(m & ((1ull << lane) - 1ull));
    if (nz) {
      int pidx = base + offl;
      if (pidx < KMAX) colp[row * KMAX + pidx] = j;
    }
    base += __popcll(m);
  }
  if (lane == 0) degp[row] = base < KMAX ? base : KMAX;
}

// ---------------------------------------------------------------------------
// GAT1: grid (192 graphs, 4 heads). K/V bf16 in LDS, stride 18 (36B rows:
// dword-aligned, odd dword stride 9 -> bank-spread). Scores bounded -> no
// online max. Output h1 bf16 [g][n][64], relu fused.
// ---------------------------------------------------------------------------
__global__ __launch_bounds__(256) void gat1_k(
    const float* __restrict__ xin, const float* __restrict__ g1,
    const int* __restrict__ colp, const int* __restrict__ degp,
    unsigned short* __restrict__ h1b) {
  __shared__ float xs[NN * 3];
  __shared__ float w1s[768];
  __shared__ unsigned short kb[NN * 18];
  __shared__ unsigned short vb[NN * 18];
  const int tid = threadIdx.x;
  const int g = blockIdx.x, co = blockIdx.y * 16;
  for (int e = tid; e < NN * 3; e += 256) xs[e] = xin[g * NN * 3 + e];
  for (int e = tid; e < 768; e += 256) w1s[e] = g1[e];
  __syncthreads();
  for (int e = tid; e < NN * 16; e += 256) {
    int n = e >> 4, c = e & 15;
    float x0 = xs[n * 3], x1 = xs[n * 3 + 1], x2 = xs[n * 3 + 2];
    int wc = co + c;
    float kk = w1s[448 + wc] + x0 * w1s[256 + wc] + x1 * w1s[320 + wc] + x2 * w1s[384 + wc];
    float vv = w1s[704 + wc] + x0 * w1s[512 + wc] + x1 * w1s[576 + wc] + x2 * w1s[640 + wc];
    kb[n * 18 + c] = f2bf(kk);
    vb[n * 18 + c] = f2bf(vv);
  }
  __syncthreads();
  for (int i = tid; i < NN; i += 256) {
    float x0 = xs[i * 3], x1 = xs[i * 3 + 1], x2 = xs[i * 3 + 2];
    float q[16], o[16];
    #pragma unroll
    for (int c = 0; c < 16; ++c) {
      int wc = co + c;
      q[c] = w1s[192 + wc] + x0 * w1s[wc] + x1 * w1s[64 + wc] + x2 * w1s[128 + wc];
      o[c] = 0.f;
    }
    int dg = degp[i];
    const int* cols = colp + i * KMAX;
    float l = 0.f;
    for (int e = 0; e < dg; ++e) {
      int j = cols[e];
      const unsigned* kr = (const unsigned*)(kb + j * 18);
      const unsigned* vr = (const unsigned*)(vb + j * 18);
      float s = 0.f;
      #pragma unroll
      for (int c = 0; c < 8; ++c) {
        unsigned u = kr[c];
        s += q[2 * c] * bflo(u) + q[2 * c + 1] * bfhi(u);
      }
      float p = __expf(s * 0.25f);
      l += p;
      #pragma unroll
      for (int c = 0; c < 8; ++c) {
        unsigned u = vr[c];
        o[2 * c]     += p * bflo(u);
        o[2 * c + 1] += p * bfhi(u);
      }
    }
    float inv = 1.f / l;
    unsigned* hr = (unsigned*)(h1b + ((size_t)g * NN + i) * 64 + co);
    #pragma unroll
    for (int c = 0; c < 8; ++c)
      hr[c] = packbf(fmaxf(o[2 * c] * inv, 0.f), fmaxf(o[2 * c + 1] * inv, 0.f));
  }
}

// ---------------------------------------------------------------------------
// GAT2 Q/K/V projection: GEMM [76800,64] x [64,96]. 1200 blocks x 64 nodes.
// ---------------------------------------------------------------------------
__global__ __launch_bounds__(256) void gat2_proj_k(
    const unsigned short* __restrict__ h1b, const float* __restrict__ g2,
    unsigned short* __restrict__ q2b, unsigned short* __restrict__ k2g,
    unsigned short* __restrict__ v2g) {
  __shared__ float ht[64 * 65];
  __shared__ float wqs[2048], wks[2048], wvs[2048];
  __shared__ float bqs[32], bks[32], bvs[32];
  const int tid = threadIdx.x, t = blockIdx.x;
  for (int e = tid; e < 2048; e += 256) {
    unsigned u = ((const unsigned*)h1b)[t * 2048 + e];
    int ln = e >> 5, d = (e & 31) * 2;
    ht[ln * 65 + d] = bflo(u);
    ht[ln * 65 + d + 1] = bfhi(u);
  }
  for (int e = tid; e < 2048; e += 256) {
    wqs[e] = g2[e]; wks[e] = g2[2080 + e]; wvs[e] = g2[4160 + e];
  }
  if (tid < 32) { bqs[tid] = g2[2048 + tid]; bks[tid] = g2[4128 + tid]; bvs[tid] = g2[6208 + tid]; }
  __syncthreads();
  const int c = tid & 31, ng = tid >> 5;
  float qa[8], ka[8], va[8];
  #pragma unroll
  for (int k = 0; k < 8; ++k) { qa[k] = bqs[c]; ka[k] = bks[c]; va[k] = bvs[c]; }
  for (int d = 0; d < 64; ++d) {
    float wq = wqs[d * 32 + c], wk = wks[d * 32 + c], wv = wvs[d * 32 + c];
    #pragma unroll
    for (int k = 0; k < 8; ++k) {
      float hv = ht[(ng * 8 + k) * 65 + d];
      qa[k] += hv * wq; ka[k] += hv * wk; va[k] += hv * wv;
    }
  }
  #pragma unroll
  for (int k = 0; k < 8; ++k) {
    int gn = t * 64 + ng * 8 + k;
    q2b[gn * 32 + c] = f2bf(qa[k]);
    k2g[gn * 32 + c] = f2bf(ka[k]);
    v2g[gn * 32 + c] = f2bf(va[k]);
  }
}

// ---------------------------------------------------------------------------
// GAT2 attention + residual + LN. grid (192, 2): 200 nodes/block, full-graph
// K/V staged bf16 stride 34 (68B rows, odd dword stride 17). Writes spo in
// [b][n][s][32] layout so temporal reads are contiguous.
// ---------------------------------------------------------------------------
__global__ __launch_bounds__(256) void gat2_attn_k(
    const float* __restrict__ xin, const unsigned short* __restrict__ q2b,
    const unsigned short* __restrict__ k2g, const unsigned short* __restrict__ v2g,
    const float* __restrict__ spw, const int* __restrict__ colp,
    const int* __restrict__ degp, float* __restrict__ spo) {
  __shared__ unsigned short k2s[NN * 34];
  __shared__ unsigned short v2s[NN * 34];
  __shared__ float gw[64];
  const int tid = threadIdx.x;
  const int g = blockIdx.x;
  if (tid < 64) gw[tid] = spw[tid];
  for (int e = tid; e < 6400; e += 256) {
    unsigned uk = ((const unsigned*)k2g)[g * 6400 + e];
    unsigned uv = ((const unsigned*)v2g)[g * 6400 + e];
    int n = e >> 4, c = (e & 15) * 2;
    *(unsigned*)(k2s + n * 34 + c) = uk;
    *(unsigned*)(v2s + n * 34 + c) = uv;
  }
  __syncthreads();
  const int b = g / 24, st = g % 24;
  const int i0 = blockIdx.y * 200;
  for (int i = i0 + tid; i < i0 + 200; i += 256) {
    const unsigned* qr = (const unsigned*)(q2b + ((size_t)g * NN + i) * 32);
    float q[32], o[32];
    #pragma unroll
    for (int c = 0; c < 16; ++c) {
      unsigned u = qr[c];
      q[2 * c] = bflo(u); q[2 * c + 1] = bfhi(u);
      o[2 * c] = 0.f; o[2 * c + 1] = 0.f;
    }
    int dg = degp[i];
    const int* cols = colp + i * KMAX;
    float l = 0.f;
    for (int e = 0; e < dg; ++e) {
      int j = cols[e];
      const unsigned* kr = (const unsigned*)(k2s + j * 34);
      float s = 0.f;
      #pragma unroll
      for (int c = 0; c < 16; ++c) {
        unsigned u = kr[c];
        s += q[2 * c] * bflo(u) + q[2 * c + 1] * bfhi(u);
      }
      float p = __expf(s * 0.17677669529663688f);
      l += p;
      const unsigned* vr = (const unsigned*)(v2s + j * 34);
      #pragma unroll
      for (int c = 0; c < 16; ++c) {
        unsigned u = vr[c];
        o[2 * c]     += p * bflo(u);
        o[2 * c + 1] += p * bfhi(u);
      }
    }
    float inv = 1.f / l;
    const float* xr = xin + ((size_t)g * NN + i) * 3;
    float row[32];
    #pragma unroll
    for (int c = 0; c < 32; ++c) row[c] = o[c] * inv;
    row[0] += xr[0]; row[1] += xr[1]; row[2] += xr[2];
    float mean = 0.f;
    #pragma unroll
    for (int c = 0; c < 32; ++c) mean += row[c];
    mean *= (1.f / 32.f);
    float var = 0.f;
    #pragma unroll
    for (int c = 0; c < 32; ++c) { float dd = row[c] - mean; var += dd * dd; }
    var *= (1.f / 32.f);
    float rinv = 1.f / sqrtf(var + 1e-6f);
    float* so = spo + (((size_t)b * NN + i) * 24 + st) * 32;
    float4* so4 = (float4*)so;
    #pragma unroll
    for (int k = 0; k < 8; ++k) {
      float4 v;
      v.x = gw[4 * k]     * (row[4 * k]     - mean) * rinv + gw[32 + 4 * k];
      v.y = gw[4 * k + 1] * (row[4 * k + 1] - mean) * rinv + gw[33 + 4 * k];
      v.z = gw[4 * k + 2] * (row[4 * k + 2] - mean) * rinv + gw[34 + 4 * k];
      v.w = gw[4 * k + 3] * (row[4 * k + 3] - mean) * rinv + gw[35 + 4 * k];
      so4[k] = v;
    }
  }
}

// ---------------------------------------------------------------------------
// Temporal transformer + fuse. LDS aliased (29.9 KB), rows padded 65/25/33 to
// kill bank conflicts, register-resident weight columns for QKV/FF1.
// ---------------------------------------------------------------------------
__global__ __launch_bounds__(128) void temporal_k(
    const float* __restrict__ sp, const float* __restrict__ tw,
    const int* __restrict__ flag, void* __restrict__ outp) {
  __shared__ float sm[7472];
  float* t_s = sm;             // [24][32]
  float* q_s = sm + 768;       // [24][65]
  float* k_s = sm + 2328;      // [24][65]
  float* v_s = sm + 3888;      // [24][65]
  float* aw  = sm + 5448;      // [48][25]
  float* x1s = sm + 6648;      // [24][33]
  float* red = sm + 7440;      // [32]
  float* att = q_s;            // alias: q dead after scores
  float* f1s = k_s;            // alias: k dead after scores ([24][64] linear)
  float* tos = v_s;            // alias: v dead after att    ([24][33])
  const int tid = threadIdx.x;

  const float* twq = tw;            const float* tbq = tw + 2048;
  const float* twk = tw + 2112;     const float* tbk = tw + 4160;
  const float* twv = tw + 4224;     const float* tbv = tw + 6272;
  const float* two = tw + 6336;     const float* tbo = tw + 8384;
  const float* fw1 = tw + 8416;     const float* fb1 = tw + 10464;
  const float* fw2 = tw + 10528;    const float* fb2 = tw + 12576;
  const float* l1g = tw + 12608;    const float* l1b = tw + 12640;
  const float* l2g = tw + 12672;    const float* l2b = tw + 12704;
  const float* fng = tw + 12736;    const float* fnb = tw + 12768;
  const float* fdw = tw + 12800;    const float* fdb = tw + 12832;

  const float4* base4 = (const float4*)(sp + (size_t)blockIdx.x * 768);
  for (int e = tid; e < 192; e += 128) ((float4*)t_s)[e] = base4[e];
  __syncthreads();

  // QKV: thread owns column hk; weights in registers, t_s broadcast reads.
  {
    const int hk = tid & 63, sh = tid >> 6;
    for (int a = 0; a < 3; ++a) {
      const float* W  = (a == 0) ? twq : (a == 1) ? twk : twv;
      const float* Bb = (a == 0) ? tbq : (a == 1) ? tbk : tbv;
      float* dst      = (a == 0) ? q_s : (a == 1) ? k_s : v_s;
      float w[32];
      #pragma unroll
      for (int c = 0; c < 32; ++c) w[c] = W[c * 64 + hk];
      float bias = Bb[hk];
      for (int s = sh * 12; s < sh * 12 + 12; ++s) {
        float acc = bias;
        const float* tr = t_s + s * 32;
        #pragma unroll
        for (int c = 0; c < 32; ++c) acc += tr[c] * w[c];
        dst[s * 65 + hk] = acc;
      }
    }
  }
  __syncthreads();

  // scores + softmax: 96 lanes, 12 keys each, pair-combine via shfl_xor.
  if (tid < 96) {
    const int h = tid / 48, rem = tid % 48, qs = rem >> 1, half = rem & 1;
    const float* qr = q_s + qs * 65 + h * 32;
    float sc[12], l = 0.f;
    #pragma unroll
    for (int k = 0; k < 12; ++k) {
      const float* kr = k_s + (half * 12 + k) * 65 + h * 32;
      float s = 0.f;
      #pragma unroll
      for (int d = 0; d < 32; ++d) s += qr[d] * kr[d];
      sc[k] = __expf(s * 0.17677669529663688f);
      l += sc[k];
    }
    l += __shfl_xor(l, 1);
    float inv = 1.f / l;
    float* ar = aw + (h * 24 + qs) * 25 + half * 12;
    #pragma unroll
    for (int k = 0; k < 12; ++k) ar[k] = sc[k] * inv;
  }
  __syncthreads();

  // attention output (writes att = q_s alias)
  for (int e = tid; e < 1536; e += 128) {
    int qs = e >> 6, hk = e & 63, h = hk >> 5;
    const float* ar = aw + (h * 24 + qs) * 25;
    float a = 0.f;
    #pragma unroll
    for (int ss = 0; ss < 24; ++ss) a += ar[ss] * v_s[ss * 65 + hk];
    att[qs * 65 + hk] = a;
  }
  __syncthreads();

  // output projection + residual
  for (int e = tid; e < 768; e += 128) {
    int s = e >> 5, c = e & 31;
    const float* ar = att + s * 65;
    float a = tbo[c];
    #pragma unroll 8
    for (int hk = 0; hk < 64; ++hk) a += ar[hk] * two[hk * 32 + c];
    x1s[s * 33 + c] = t_s[e] + a;
  }
  __syncthreads();
  if (tid < 24) {  // LN1 (stride-33 rows: lanes hit distinct banks)
    float* r = x1s + tid * 33;
    float mean = 0.f;
    for (int c = 0; c < 32; ++c) mean += r[c];
    mean *= (1.f / 32.f);
    float var = 0.f;
    for (int c = 0; c < 32; ++c) { float d = r[c] - mean; var += d * d; }
    var *= (1.f / 32.f);
    float ri = 1.f / sqrtf(var + 1e-6f);
    for (int c = 0; c < 32; ++c) r[c] = l1g[c] * (r[c] - mean) * ri + l1b[c];
  }
  __syncthreads();

  // FF1 + exact gelu (writes f1s = k_s alias)
  {
    const int j = tid & 63, sh = tid >> 6;
    float w[32];
    #pragma unroll
    for (int c = 0; c < 32; ++c) w[c] = fw1[c * 64 + j];
    float bias = fb1[j];
    for (int s = sh * 12; s < sh * 12 + 12; ++s) {
      float acc = bias;
      const float* xr = x1s + s * 33;
      #pragma unroll
      for (int c = 0; c < 32; ++c) acc += xr[c] * w[c];
      f1s[s * 64 + j] = 0.5f * acc * (1.f + erff(acc * 0.70710678118654752f));
    }
  }
  __syncthreads();

  // FF2 + residual (writes tos = v_s alias)
  for (int e = tid; e < 768; e += 128) {
    int s = e >> 5, c = e & 31;
    const float* fr = f1s + s * 64;
    float a = fb2[c];
    #pragma unroll 8
    for (int j = 0; j < 64; ++j) a += fr[j] * fw2[j * 32 + c];
    tos[s * 33 + c] = x1s[s * 33 + c] + a;
  }
  __syncthreads();
  if (tid < 24) {  // LN2
    float* r = tos + tid * 33;
    float mean = 0.f;
    for (int c = 0; c < 32; ++c) mean += r[c];
    mean *= (1.f / 32.f);
    float var = 0.f;
    for (int c = 0; c < 32; ++c) { float d = r[c] - mean; var += d * d; }
    var *= (1.f / 32.f);
    float ri = 1.f / sqrtf(var + 1e-6f);
    for (int c = 0; c < 32; ++c) r[c] = l2g[c] * (r[c] - mean) * ri + l2b[c];
  }
  __syncthreads();

  if (tid < 32) {
    float ms = 0.f, mt = 0.f;
    for (int s = 0; s < 24; ++s) { ms += t_s[s * 32 + tid]; mt += tos[s * 33 + tid]; }
    red[tid] = (ms + mt) * (1.f / 24.f);
  }
  __syncthreads();
  if (tid == 0) {
    float mean = 0.f;
    for (int c = 0; c < 32; ++c) mean += red[c];
    mean *= (1.f / 32.f);
    float var = 0.f;
    for (int c = 0; c < 32; ++c) { float d = red[c] - mean; var += d * d; }
    var *= (1.f / 32.f);
    float ri = 1.f / sqrtf(var + 1e-6f);
    float acc = fdb[0];
    for (int c = 0; c < 32; ++c)
      acc += (fng[c] * (red[c] - mean) * ri + fnb[c]) * fdw[c];
    if (flag[0]) ((__hip_bfloat16*)outp)[blockIdx.x] = __float2bfloat16(acc);
    else         ((float*)outp)[blockIdx.x] = acc;
  }
}

// ---------------------------------------------------------------------------
extern "C" void kernel_launch(void* const* d_in, const int* in_sizes, int n_in,
                              void* d_out, int out_size, void* d_ws, size_t ws_size,
                              hipStream_t stream) {
  static const int sizes[36] = {
      230400, 160000,
      192, 64, 192, 64, 192, 64,
      2048, 32, 2048, 32, 2048, 32,
      32, 32,
      2048, 64, 2048, 64, 2048, 64, 2048, 32,
      2048, 64, 2048, 32,
      32, 32, 32, 32, 32, 32,
      32, 1};
  PtrTable pt;
  int off = 0;
  for (int i = 0; i < 36; ++i) { pt.p[i] = d_in[i]; pt.off[i] = off; off += sizes[i]; }
  pt.off[36] = off;  // 410305

  char* ws = (char*)d_ws;
  int*   flag = (int*)ws;                                  // @0
  float* conv = (float*)(ws + 64);                         // 410305 f
  int*   colp = (int*)(ws + 1835008);                      // 400*64
  int*   degp = (int*)(ws + 1937408);                      // 400
  // h1b (bf16, 9.83MB) and spo (fp32, 9.83MB) share a region: h1b is dead
  // before gat2_attn_k writes spo.
  unsigned short* h1b = (unsigned short*)(ws + 2097152);
  float*          spo = (float*)(ws + 2097152);
  unsigned short* q2b = (unsigned short*)(ws + 11927552);  // 4.92MB
  unsigned short* k2g = (unsigned short*)(ws + 16842752);  // 4.92MB
  unsigned short* v2g = (unsigned short*)(ws + 21757952);  // 4.92MB -> ends 26.7MB

  const float* cin  = conv;
  const float* cadj = conv + 230400;
  const float* g1   = conv + 390400;
  const float* g2   = conv + 391168;
  const float* spw  = conv + 397408;
  const float* twp  = conv + 397472;

  hipLaunchKernelGGL(detect_dtype_k, dim3(1), dim3(64), 0, stream,
                     (const unsigned short*)d_in[0], flag);
  hipLaunchKernelGGL(convert_k, dim3(512), dim3(256), 0, stream, pt,
                     (const int*)flag, conv);
  hipLaunchKernelGGL(build_csr_k, dim3(NN), dim3(64), 0, stream, cadj, colp, degp);
  hipLaunchKernelGGL(gat1_k, dim3(192, 4), dim3(256), 0, stream, cin, g1,
                     (const int*)colp, (const int*)degp, h1b);
  hipLaunchKernelGGL(gat2_proj_k, dim3(1200), dim3(256), 0, stream,
                     (const unsigned short*)h1b, g2, q2b, k2g, v2g);
  hipLaunchKernelGGL(gat2_attn_k, dim3(192, 2), dim3(256), 0, stream, cin,
                     (const unsigned short*)q2b, (const unsigned short*)k2g,
                     (const unsigned short*)v2g, spw, (const int*)colp,
                     (const int*)degp, spo);
  hipLaunchKernelGGL(temporal_k, dim3(3200), dim3(128), 0, stream,
                     (const float*)spo, twp, (const int*)flag, d_out);
}